// Round 1
// baseline (149.651 us; speedup 1.0000x reference)
//
#include <hip/hip_runtime.h>
#include <cstddef>

// Problem constants (from reference): S=8, N=50000, F=5, DEG=32, D_IN=D_OUT=128
static constexpr int S_   = 8;
static constexpr int N_   = 50000;
static constexpr int F_   = 5;
static constexpr int DEG_ = 32;
static constexpr int DOUT_ = 128;

// ---------------------------------------------------------------------------
// Kernel 1: fuse W_1 [5][128] with W [256][128] into Wc [2][5][128]:
//   Wc[0][f][o] = sum_d W_1[f][d] * W[d][o]        (self path)
//   Wc[1][f][o] = sum_d W_1[f][d] * W[128+d][o]    (neighbor path)
// 1280 outputs, 128-FMA each — trivial cost.
// ---------------------------------------------------------------------------
__global__ void wc_precompute(const float* __restrict__ W1,
                              const float* __restrict__ W,
                              float* __restrict__ Wc) {
    int t = blockIdx.x * blockDim.x + threadIdx.x;
    if (t >= 2 * F_ * DOUT_) return;
    int o = t & (DOUT_ - 1);
    int f = (t >> 7) % F_;
    int p = t / (F_ * DOUT_);
    const float* w1r  = W1 + f * 128;                         // W_1[f][d]
    const float* wcol = W + (size_t)p * 128 * DOUT_ + o;      // W[p*128+d][o]
    float acc = 0.f;
#pragma unroll 8
    for (int d = 0; d < 128; ++d)
        acc = fmaf(w1r[d], wcol[(size_t)d * DOUT_], acc);
    Wc[t] = acc;
}

// ---------------------------------------------------------------------------
// Kernel 2: fused encoder. One wave = 2 consecutive nodes.
//   lanes 0..31  -> node 2p   (gather its 32 neighbors)
//   lanes 32..63 -> node 2p+1
// Butterfly shfl_xor (masks 1..16) reduces neighbor features within each
// 32-lane half, leaving the sum on all lanes. Each lane then produces 4
// consecutive output channels (o = (lane&31)*4) -> one float4 store; the
// wave's stores cover 1KB contiguous.
// ---------------------------------------------------------------------------
__global__ __launch_bounds__(256) void encoder_fused(
    const float* __restrict__ x,     // [S][N][5]
    const int*   __restrict__ idx,   // [S][N][32]
    const float* __restrict__ Wc,    // [2][5][128]
    const float* __restrict__ b,     // [128]
    float* __restrict__ out,         // [S][N][128]
    int total_pairs) {
    const int lane = threadIdx.x & 63;
    const int sl   = lane & 31;
    const int half = lane >> 5;
    const int o0   = sl << 2;  // 4 consecutive output channels per lane
    const int gwave  = (blockIdx.x * blockDim.x + threadIdx.x) >> 6;
    const int nwaves = (gridDim.x * blockDim.x) >> 6;

    // Per-lane fused weights: constant over the grid-stride loop.
    float wa[F_][4], wb[F_][4];
#pragma unroll
    for (int f = 0; f < F_; ++f) {
        float4 a  = *reinterpret_cast<const float4*>(Wc + f * DOUT_ + o0);
        float4 bb = *reinterpret_cast<const float4*>(Wc + F_ * DOUT_ + f * DOUT_ + o0);
        wa[f][0] = a.x;  wa[f][1] = a.y;  wa[f][2] = a.z;  wa[f][3] = a.w;
        wb[f][0] = bb.x; wb[f][1] = bb.y; wb[f][2] = bb.z; wb[f][3] = bb.w;
    }
    const float4 bias = *reinterpret_cast<const float4*>(b + o0);

    for (int p = gwave; p < total_pairs; p += nwaves) {
        const int node = p * 2 + half;
        const int s    = node / N_;               // pairs never straddle samples (N even)
        // --- neighbor gather + mean ---
        const int nb = idx[(size_t)node * DEG_ + sl];      // coalesced 256B per wave
        const float* xr = x + ((size_t)s * N_ + nb) * F_;  // scattered, L2-resident
        float n0 = xr[0], n1 = xr[1], n2 = xr[2], n3 = xr[3], n4 = xr[4];
#pragma unroll
        for (int m = 1; m < 32; m <<= 1) {   // butterfly within each 32-lane half
            n0 += __shfl_xor(n0, m);
            n1 += __shfl_xor(n1, m);
            n2 += __shfl_xor(n2, m);
            n3 += __shfl_xor(n3, m);
            n4 += __shfl_xor(n4, m);
        }
        const float inv = 1.f / DEG_;
        const float nf[F_] = {n0 * inv, n1 * inv, n2 * inv, n3 * inv, n4 * inv};
        // --- self features (broadcast load across the half) ---
        const float* xs = x + (size_t)node * F_;
        const float sf[F_] = {xs[0], xs[1], xs[2], xs[3], xs[4]};
        // --- 4 output channels ---
        float y0 = bias.x, y1 = bias.y, y2 = bias.z, y3 = bias.w;
#pragma unroll
        for (int f = 0; f < F_; ++f) {
            y0 = fmaf(sf[f], wa[f][0], y0); y0 = fmaf(nf[f], wb[f][0], y0);
            y1 = fmaf(sf[f], wa[f][1], y1); y1 = fmaf(nf[f], wb[f][1], y1);
            y2 = fmaf(sf[f], wa[f][2], y2); y2 = fmaf(nf[f], wb[f][2], y2);
            y3 = fmaf(sf[f], wa[f][3], y3); y3 = fmaf(nf[f], wb[f][3], y3);
        }
        float4 yv = make_float4(fmaxf(y0, 0.f), fmaxf(y1, 0.f),
                                fmaxf(y2, 0.f), fmaxf(y3, 0.f));
        *reinterpret_cast<float4*>(out + (size_t)node * DOUT_ + o0) = yv;
    }
}

extern "C" void kernel_launch(void* const* d_in, const int* in_sizes, int n_in,
                              void* d_out, int out_size, void* d_ws, size_t ws_size,
                              hipStream_t stream) {
    const float* x   = (const float*)d_in[0];
    const int*   idx = (const int*)  d_in[1];
    const float* W1  = (const float*)d_in[2];
    const float* W   = (const float*)d_in[3];
    const float* b   = (const float*)d_in[4];
    float* out = (float*)d_out;
    float* Wc  = (float*)d_ws;   // needs 2*5*128*4 = 5120 bytes

    hipLaunchKernelGGL(wc_precompute, dim3(5), dim3(256), 0, stream, W1, W, Wc);

    const int total_pairs = S_ * N_ / 2;  // 200000
    const int blocks = 2048;              // 8192 waves, ~24 pairs each (grid-stride)
    hipLaunchKernelGGL(encoder_fused, dim3(blocks), dim3(256), 0, stream,
                       x, idx, Wc, b, out, total_pairs);
}

// Round 3
// 145.521 us; speedup vs baseline: 1.0284x; 1.0284x over previous
//
#include <hip/hip_runtime.h>
#include <cstddef>
#include <cstdint>

// Problem constants: S=8, N=50000, F=5, DEG=32, D_IN=D_OUT=128
static constexpr int S_    = 8;
static constexpr int N_    = 50000;
static constexpr int F_    = 5;
static constexpr int DEG_  = 32;
static constexpr int DOUT_ = 128;

// Native clang vector types — required by __builtin_nontemporal_{load,store}.
typedef float  f32x4 __attribute__((ext_vector_type(4)));
typedef int    i32x4 __attribute__((ext_vector_type(4)));

// ---------------------------------------------------------------------------
// Kernel 1: fuse W_1 [5][128] with W [256][128] into Wc [2][5][128].
// ---------------------------------------------------------------------------
__global__ void wc_precompute(const float* __restrict__ W1,
                              const float* __restrict__ W,
                              float* __restrict__ Wc) {
    int t = blockIdx.x * blockDim.x + threadIdx.x;
    if (t >= 2 * F_ * DOUT_) return;
    int o = t & (DOUT_ - 1);
    int f = (t >> 7) % F_;
    int p = t / (F_ * DOUT_);
    const float* w1r  = W1 + f * 128;
    const float* wcol = W + (size_t)p * 128 * DOUT_ + o;
    float acc = 0.f;
#pragma unroll 8
    for (int d = 0; d < 128; ++d)
        acc = fmaf(w1r[d], wcol[(size_t)d * DOUT_], acc);
    Wc[t] = acc;
}

// ---------------------------------------------------------------------------
// Kernel 2: pack x rows (5 fp32, 20B unaligned) into 16B-aligned f16x8 rows.
// Gather then needs ONE dwordx4 per neighbor instead of 5 unaligned dwords.
// ---------------------------------------------------------------------------
struct alignas(16) H8 { _Float16 v[8]; };

__global__ __launch_bounds__(256) void xpack_f16(const float* __restrict__ x,
                                                 H8* __restrict__ xh) {
    int t = blockIdx.x * blockDim.x + threadIdx.x;
    if (t >= S_ * N_) return;
    const float* r = x + (size_t)t * F_;
    H8 o;
#pragma unroll
    for (int f = 0; f < F_; ++f) o.v[f] = (_Float16)r[f];
#pragma unroll
    for (int f = F_; f < 8; ++f) o.v[f] = (_Float16)0.f;
    xh[t] = o;
}

// ---------------------------------------------------------------------------
// Kernel 3: fused encoder, f16 gather path. One wave = 2 pairs = 4 nodes
// per iteration (two independent gather->butterfly chains for MLP).
// lanes 0..31 -> even node of each pair, lanes 32..63 -> odd node.
// ---------------------------------------------------------------------------
__global__ __launch_bounds__(256) void encoder_f16(
    const float* __restrict__ x,     // [S][N][5] fp32 (self features, exact)
    const int*   __restrict__ idx,   // [S][N][32]
    const H8*    __restrict__ xh,    // [S*N] packed f16 rows (gather source)
    const float* __restrict__ Wc,    // [2][5][128]
    const float* __restrict__ b,     // [128]
    float* __restrict__ out,         // [S][N][128]
    int total_pairs) {
    const int lane = threadIdx.x & 63;
    const int sl   = lane & 31;
    const int half = lane >> 5;
    const int o0   = sl << 2;
    const int gwave  = (blockIdx.x * blockDim.x + threadIdx.x) >> 6;
    const int nwaves = (gridDim.x * blockDim.x) >> 6;

    float wa[F_][4], wb[F_][4];
#pragma unroll
    for (int f = 0; f < F_; ++f) {
        float4 a  = *reinterpret_cast<const float4*>(Wc + f * DOUT_ + o0);
        float4 bb = *reinterpret_cast<const float4*>(Wc + F_ * DOUT_ + f * DOUT_ + o0);
        wa[f][0] = a.x;  wa[f][1] = a.y;  wa[f][2] = a.z;  wa[f][3] = a.w;
        wb[f][0] = bb.x; wb[f][1] = bb.y; wb[f][2] = bb.z; wb[f][3] = bb.w;
    }
    const float4 bias = *reinterpret_cast<const float4*>(b + o0);
    const float inv = 1.f / DEG_;

    // total_pairs is even; q and q+1 are both valid whenever q < total_pairs.
    for (int q = gwave * 2; q < total_pairs; q += nwaves * 2) {
        const int nodeA = 2 * q + half;
        const int nodeB = nodeA + 2;
        const int sA = nodeA / N_;
        const int sB = nodeB / N_;   // block of 4 nodes can straddle a sample

        // --- issue both idx loads + both gathers up front (ILP) ---
        const int nbA = __builtin_nontemporal_load(idx + (size_t)nodeA * DEG_ + sl);
        const int nbB = __builtin_nontemporal_load(idx + (size_t)nodeB * DEG_ + sl);
        union { i32x4 i; H8 h; } uA, uB;
        uA.i = *reinterpret_cast<const i32x4*>(xh + (size_t)sA * N_ + nbA);
        uB.i = *reinterpret_cast<const i32x4*>(xh + (size_t)sB * N_ + nbB);

        float a0 = (float)uA.h.v[0], a1 = (float)uA.h.v[1], a2 = (float)uA.h.v[2],
              a3 = (float)uA.h.v[3], a4 = (float)uA.h.v[4];
        float c0 = (float)uB.h.v[0], c1 = (float)uB.h.v[1], c2 = (float)uB.h.v[2],
              c3 = (float)uB.h.v[3], c4 = (float)uB.h.v[4];

#pragma unroll
        for (int m = 1; m < 32; m <<= 1) {   // two independent butterflies
            a0 += __shfl_xor(a0, m); c0 += __shfl_xor(c0, m);
            a1 += __shfl_xor(a1, m); c1 += __shfl_xor(c1, m);
            a2 += __shfl_xor(a2, m); c2 += __shfl_xor(c2, m);
            a3 += __shfl_xor(a3, m); c3 += __shfl_xor(c3, m);
            a4 += __shfl_xor(a4, m); c4 += __shfl_xor(c4, m);
        }
        const float nfA[F_] = {a0 * inv, a1 * inv, a2 * inv, a3 * inv, a4 * inv};
        const float nfB[F_] = {c0 * inv, c1 * inv, c2 * inv, c3 * inv, c4 * inv};

        // --- self features, fp32 exact (2 rows/half-wave, broadcast) ---
        const float* xsA = x + (size_t)nodeA * F_;
        const float* xsB = x + (size_t)nodeB * F_;
        float sfA[F_], sfB[F_];
#pragma unroll
        for (int f = 0; f < F_; ++f) { sfA[f] = xsA[f]; sfB[f] = xsB[f]; }

        float y0 = bias.x, y1 = bias.y, y2 = bias.z, y3 = bias.w;
        float z0 = bias.x, z1 = bias.y, z2 = bias.z, z3 = bias.w;
#pragma unroll
        for (int f = 0; f < F_; ++f) {
            y0 = fmaf(sfA[f], wa[f][0], y0); y0 = fmaf(nfA[f], wb[f][0], y0);
            y1 = fmaf(sfA[f], wa[f][1], y1); y1 = fmaf(nfA[f], wb[f][1], y1);
            y2 = fmaf(sfA[f], wa[f][2], y2); y2 = fmaf(nfA[f], wb[f][2], y2);
            y3 = fmaf(sfA[f], wa[f][3], y3); y3 = fmaf(nfA[f], wb[f][3], y3);
            z0 = fmaf(sfB[f], wa[f][0], z0); z0 = fmaf(nfB[f], wb[f][0], z0);
            z1 = fmaf(sfB[f], wa[f][1], z1); z1 = fmaf(nfB[f], wb[f][1], z1);
            z2 = fmaf(sfB[f], wa[f][2], z2); z2 = fmaf(nfB[f], wb[f][2], z2);
            z3 = fmaf(sfB[f], wa[f][3], z3); z3 = fmaf(nfB[f], wb[f][3], z3);
        }
        f32x4 yv = { fmaxf(y0, 0.f), fmaxf(y1, 0.f), fmaxf(y2, 0.f), fmaxf(y3, 0.f) };
        f32x4 zv = { fmaxf(z0, 0.f), fmaxf(z1, 0.f), fmaxf(z2, 0.f), fmaxf(z3, 0.f) };
        __builtin_nontemporal_store(yv,
            reinterpret_cast<f32x4*>(out + (size_t)nodeA * DOUT_ + o0));
        __builtin_nontemporal_store(zv,
            reinterpret_cast<f32x4*>(out + (size_t)nodeB * DOUT_ + o0));
    }
}

// ---------------------------------------------------------------------------
// Fallback (round-1 fp32 path) if ws_size is too small for the pack buffer.
// ---------------------------------------------------------------------------
__global__ __launch_bounds__(256) void encoder_f32(
    const float* __restrict__ x, const int* __restrict__ idx,
    const float* __restrict__ Wc, const float* __restrict__ b,
    float* __restrict__ out, int total_pairs) {
    const int lane = threadIdx.x & 63;
    const int sl   = lane & 31;
    const int half = lane >> 5;
    const int o0   = sl << 2;
    const int gwave  = (blockIdx.x * blockDim.x + threadIdx.x) >> 6;
    const int nwaves = (gridDim.x * blockDim.x) >> 6;
    float wa[F_][4], wb[F_][4];
#pragma unroll
    for (int f = 0; f < F_; ++f) {
        float4 a  = *reinterpret_cast<const float4*>(Wc + f * DOUT_ + o0);
        float4 bb = *reinterpret_cast<const float4*>(Wc + F_ * DOUT_ + f * DOUT_ + o0);
        wa[f][0] = a.x;  wa[f][1] = a.y;  wa[f][2] = a.z;  wa[f][3] = a.w;
        wb[f][0] = bb.x; wb[f][1] = bb.y; wb[f][2] = bb.z; wb[f][3] = bb.w;
    }
    const float4 bias = *reinterpret_cast<const float4*>(b + o0);
    for (int p = gwave; p < total_pairs; p += nwaves) {
        const int node = p * 2 + half;
        const int s    = node / N_;
        const int nb = idx[(size_t)node * DEG_ + sl];
        const float* xr = x + ((size_t)s * N_ + nb) * F_;
        float n0 = xr[0], n1 = xr[1], n2 = xr[2], n3 = xr[3], n4 = xr[4];
#pragma unroll
        for (int m = 1; m < 32; m <<= 1) {
            n0 += __shfl_xor(n0, m); n1 += __shfl_xor(n1, m); n2 += __shfl_xor(n2, m);
            n3 += __shfl_xor(n3, m); n4 += __shfl_xor(n4, m);
        }
        const float inv = 1.f / DEG_;
        const float nf[F_] = {n0 * inv, n1 * inv, n2 * inv, n3 * inv, n4 * inv};
        const float* xs = x + (size_t)node * F_;
        const float sf[F_] = {xs[0], xs[1], xs[2], xs[3], xs[4]};
        float y0 = bias.x, y1 = bias.y, y2 = bias.z, y3 = bias.w;
#pragma unroll
        for (int f = 0; f < F_; ++f) {
            y0 = fmaf(sf[f], wa[f][0], y0); y0 = fmaf(nf[f], wb[f][0], y0);
            y1 = fmaf(sf[f], wa[f][1], y1); y1 = fmaf(nf[f], wb[f][1], y1);
            y2 = fmaf(sf[f], wa[f][2], y2); y2 = fmaf(nf[f], wb[f][2], y2);
            y3 = fmaf(sf[f], wa[f][3], y3); y3 = fmaf(nf[f], wb[f][3], y3);
        }
        float4 yv = make_float4(fmaxf(y0, 0.f), fmaxf(y1, 0.f),
                                fmaxf(y2, 0.f), fmaxf(y3, 0.f));
        *reinterpret_cast<float4*>(out + (size_t)node * DOUT_ + o0) = yv;
    }
}

extern "C" void kernel_launch(void* const* d_in, const int* in_sizes, int n_in,
                              void* d_out, int out_size, void* d_ws, size_t ws_size,
                              hipStream_t stream) {
    const float* x   = (const float*)d_in[0];
    const int*   idx = (const int*)  d_in[1];
    const float* W1  = (const float*)d_in[2];
    const float* W   = (const float*)d_in[3];
    const float* b   = (const float*)d_in[4];
    float* out = (float*)d_out;

    const size_t wc_bytes = (size_t)2 * F_ * DOUT_ * sizeof(float);   // 5120
    const size_t xh_bytes = (size_t)S_ * N_ * sizeof(H8);             // 6.4 MB
    float* Wc = (float*)d_ws;

    hipLaunchKernelGGL(wc_precompute, dim3(5), dim3(256), 0, stream, W1, W, Wc);

    const int total_pairs = S_ * N_ / 2;  // 200000
    const int blocks = 2048;

    if (ws_size >= wc_bytes + xh_bytes) {
        H8* xh = (H8*)((char*)d_ws + wc_bytes);   // 5120 % 16 == 0
        hipLaunchKernelGGL(xpack_f16, dim3((S_ * N_ + 255) / 256), dim3(256),
                           0, stream, x, xh);
        hipLaunchKernelGGL(encoder_f16, dim3(blocks), dim3(256), 0, stream,
                           x, idx, xh, Wc, b, out, total_pairs);
    } else {
        hipLaunchKernelGGL(encoder_f32, dim3(blocks), dim3(256), 0, stream,
                           x, idx, Wc, b, out, total_pairs);
    }
}

// Round 4
// 129.024 us; speedup vs baseline: 1.1599x; 1.1279x over previous
//
#include <hip/hip_runtime.h>
#include <cstddef>
#include <cstdint>

// Problem constants: S=8, N=50000, F=5, DEG=32, D_IN=D_OUT=128
static constexpr int S_    = 8;
static constexpr int N_    = 50000;
static constexpr int F_    = 5;
static constexpr int DEG_  = 32;
static constexpr int DOUT_ = 128;
static constexpr int TOTAL_NODES = S_ * N_;            // 400000
static constexpr int NODES_PER_WAVE = 8;               // 4 chains x 2 halves
static constexpr int GROUPS = TOTAL_NODES / NODES_PER_WAVE;  // 50000 (exact)

typedef float    f32x4 __attribute__((ext_vector_type(4)));
typedef int      i32x4 __attribute__((ext_vector_type(4)));
typedef _Float16 h2    __attribute__((ext_vector_type(2)));

// ---------------------------------------------------------------------------
// Kernel 1: fuse W_1 [5][128] with W [256][128] into Wc [2][5][128].
// ---------------------------------------------------------------------------
__global__ void wc_precompute(const float* __restrict__ W1,
                              const float* __restrict__ W,
                              float* __restrict__ Wc) {
    int t = blockIdx.x * blockDim.x + threadIdx.x;
    if (t >= 2 * F_ * DOUT_) return;
    int o = t & (DOUT_ - 1);
    int f = (t >> 7) % F_;
    int p = t / (F_ * DOUT_);
    const float* w1r  = W1 + f * 128;
    const float* wcol = W + (size_t)p * 128 * DOUT_ + o;
    float acc = 0.f;
#pragma unroll 8
    for (int d = 0; d < 128; ++d)
        acc = fmaf(w1r[d], wcol[(size_t)d * DOUT_], acc);
    Wc[t] = acc;
}

// ---------------------------------------------------------------------------
// Kernel 2: pack x rows (5 fp32, 20B) into 16B-aligned f16x8 rows.
// ---------------------------------------------------------------------------
struct alignas(16) H8 { _Float16 v[8]; };

__global__ __launch_bounds__(256) void xpack_f16(const float* __restrict__ x,
                                                 H8* __restrict__ xh) {
    int t = blockIdx.x * blockDim.x + threadIdx.x;
    if (t >= TOTAL_NODES) return;
    const float* r = x + (size_t)t * F_;
    H8 o;
#pragma unroll
    for (int f = 0; f < F_; ++f) o.v[f] = (_Float16)r[f];
#pragma unroll
    for (int f = F_; f < 8; ++f) o.v[f] = (_Float16)0.f;
    xh[t] = o;
}

// ---------------------------------------------------------------------------
// Kernel 3: fused encoder v3.
//   One wave = one group of 8 consecutive nodes (exact dispatch, no loop).
//   4 independent chains j=0..3; chain j handles nodes base+half+2j for the
//   two 32-lane halves. All idx / gather / self loads issued up front (MLP).
//   Neighbor reduce: butterfly on 3 packed-f16 dwords (15 shfl + 15 pk_add).
//   50000 % 8 == 0, so a group never straddles a sample boundary.
// ---------------------------------------------------------------------------
__global__ __launch_bounds__(256) void encoder_v3(
    const int*   __restrict__ idx,   // [S][N][32]
    const H8*    __restrict__ xh,    // [S*N] packed f16 rows
    const float* __restrict__ Wc,    // [2][5][128]
    const float* __restrict__ b,     // [128]
    float* __restrict__ out) {       // [S][N][128]
    const int lane = threadIdx.x & 63;
    const int sl   = lane & 31;
    const int half = lane >> 5;
    const int o0   = sl << 2;
    const int g    = (blockIdx.x * blockDim.x + threadIdx.x) >> 6;  // 0..49999

    // Per-lane fused weight fragments (coalesced 16B/lane).
    float wa[F_][4], wb[F_][4];
#pragma unroll
    for (int f = 0; f < F_; ++f) {
        f32x4 a  = *reinterpret_cast<const f32x4*>(Wc + f * DOUT_ + o0);
        f32x4 bb = *reinterpret_cast<const f32x4*>(Wc + F_ * DOUT_ + f * DOUT_ + o0);
        wa[f][0] = a.x;  wa[f][1] = a.y;  wa[f][2] = a.z;  wa[f][3] = a.w;
        wb[f][0] = bb.x; wb[f][1] = bb.y; wb[f][2] = bb.z; wb[f][3] = bb.w;
    }
    const f32x4 bias = *reinterpret_cast<const f32x4*>(b + o0);
    const float inv = 1.f / DEG_;

    const int base = g * NODES_PER_WAVE;
    const int s    = base / N_;                  // uniform over the group
    const H8* xs   = xh + (size_t)s * N_;

    union U { i32x4 i; h2 h[4]; };

    // --- issue ALL loads up front: 4 idx, 4 gathers, 4 self rows ---
    int node[4], nb[4];
#pragma unroll
    for (int j = 0; j < 4; ++j) {
        node[j] = base + half + 2 * j;
        nb[j] = __builtin_nontemporal_load(idx + (size_t)node[j] * DEG_ + sl);
    }
    U gv[4], sv[4];
#pragma unroll
    for (int j = 0; j < 4; ++j) {
        gv[j].i = *reinterpret_cast<const i32x4*>(xs + nb[j]);       // scattered
        sv[j].i = *reinterpret_cast<const i32x4*>(xh + node[j]);     // broadcast
    }

    // --- per-chain: packed-f16 butterfly, then MLP + store ---
#pragma unroll
    for (int j = 0; j < 4; ++j) {
        h2 v0 = gv[j].h[0], v1 = gv[j].h[1], v2 = gv[j].h[2];
#pragma unroll
        for (int m = 1; m < 32; m <<= 1) {
            v0 += __builtin_bit_cast(h2, __shfl_xor(__builtin_bit_cast(int, v0), m));
            v1 += __builtin_bit_cast(h2, __shfl_xor(__builtin_bit_cast(int, v1), m));
            v2 += __builtin_bit_cast(h2, __shfl_xor(__builtin_bit_cast(int, v2), m));
        }
        const float nf[F_] = { (float)v0.x * inv, (float)v0.y * inv,
                               (float)v1.x * inv, (float)v1.y * inv,
                               (float)v2.x * inv };
        const float sf[F_] = { (float)sv[j].h[0].x, (float)sv[j].h[0].y,
                               (float)sv[j].h[1].x, (float)sv[j].h[1].y,
                               (float)sv[j].h[2].x };
        float y0 = bias.x, y1 = bias.y, y2 = bias.z, y3 = bias.w;
#pragma unroll
        for (int f = 0; f < F_; ++f) {
            y0 = fmaf(sf[f], wa[f][0], y0); y0 = fmaf(nf[f], wb[f][0], y0);
            y1 = fmaf(sf[f], wa[f][1], y1); y1 = fmaf(nf[f], wb[f][1], y1);
            y2 = fmaf(sf[f], wa[f][2], y2); y2 = fmaf(nf[f], wb[f][2], y2);
            y3 = fmaf(sf[f], wa[f][3], y3); y3 = fmaf(nf[f], wb[f][3], y3);
        }
        f32x4 yv = { fmaxf(y0, 0.f), fmaxf(y1, 0.f), fmaxf(y2, 0.f), fmaxf(y3, 0.f) };
        __builtin_nontemporal_store(yv,
            reinterpret_cast<f32x4*>(out + (size_t)node[j] * DOUT_ + o0));
    }
}

// ---------------------------------------------------------------------------
// Fallback (fp32 path) if ws_size is too small for the pack buffer.
// ---------------------------------------------------------------------------
__global__ __launch_bounds__(256) void encoder_f32(
    const float* __restrict__ x, const int* __restrict__ idx,
    const float* __restrict__ Wc, const float* __restrict__ b,
    float* __restrict__ out, int total_pairs) {
    const int lane = threadIdx.x & 63;
    const int sl   = lane & 31;
    const int half = lane >> 5;
    const int o0   = sl << 2;
    const int gwave  = (blockIdx.x * blockDim.x + threadIdx.x) >> 6;
    const int nwaves = (gridDim.x * blockDim.x) >> 6;
    float wa[F_][4], wb[F_][4];
#pragma unroll
    for (int f = 0; f < F_; ++f) {
        f32x4 a  = *reinterpret_cast<const f32x4*>(Wc + f * DOUT_ + o0);
        f32x4 bb = *reinterpret_cast<const f32x4*>(Wc + F_ * DOUT_ + f * DOUT_ + o0);
        wa[f][0] = a.x;  wa[f][1] = a.y;  wa[f][2] = a.z;  wa[f][3] = a.w;
        wb[f][0] = bb.x; wb[f][1] = bb.y; wb[f][2] = bb.z; wb[f][3] = bb.w;
    }
    const f32x4 bias = *reinterpret_cast<const f32x4*>(b + o0);
    for (int p = gwave; p < total_pairs; p += nwaves) {
        const int node = p * 2 + half;
        const int s    = node / N_;
        const int nb = idx[(size_t)node * DEG_ + sl];
        const float* xr = x + ((size_t)s * N_ + nb) * F_;
        float n0 = xr[0], n1 = xr[1], n2 = xr[2], n3 = xr[3], n4 = xr[4];
#pragma unroll
        for (int m = 1; m < 32; m <<= 1) {
            n0 += __shfl_xor(n0, m); n1 += __shfl_xor(n1, m); n2 += __shfl_xor(n2, m);
            n3 += __shfl_xor(n3, m); n4 += __shfl_xor(n4, m);
        }
        const float inv = 1.f / DEG_;
        const float nf[F_] = {n0 * inv, n1 * inv, n2 * inv, n3 * inv, n4 * inv};
        const float* xsp = x + (size_t)node * F_;
        const float sf[F_] = {xsp[0], xsp[1], xsp[2], xsp[3], xsp[4]};
        float y0 = bias.x, y1 = bias.y, y2 = bias.z, y3 = bias.w;
#pragma unroll
        for (int f = 0; f < F_; ++f) {
            y0 = fmaf(sf[f], wa[f][0], y0); y0 = fmaf(nf[f], wb[f][0], y0);
            y1 = fmaf(sf[f], wa[f][1], y1); y1 = fmaf(nf[f], wb[f][1], y1);
            y2 = fmaf(sf[f], wa[f][2], y2); y2 = fmaf(nf[f], wb[f][2], y2);
            y3 = fmaf(sf[f], wa[f][3], y3); y3 = fmaf(nf[f], wb[f][3], y3);
        }
        f32x4 yv = { fmaxf(y0, 0.f), fmaxf(y1, 0.f), fmaxf(y2, 0.f), fmaxf(y3, 0.f) };
        *reinterpret_cast<f32x4*>(out + (size_t)node * DOUT_ + o0) = yv;
    }
}

extern "C" void kernel_launch(void* const* d_in, const int* in_sizes, int n_in,
                              void* d_out, int out_size, void* d_ws, size_t ws_size,
                              hipStream_t stream) {
    const float* x   = (const float*)d_in[0];
    const int*   idx = (const int*)  d_in[1];
    const float* W1  = (const float*)d_in[2];
    const float* W   = (const float*)d_in[3];
    const float* b   = (const float*)d_in[4];
    float* out = (float*)d_out;

    const size_t wc_bytes = (size_t)2 * F_ * DOUT_ * sizeof(float);   // 5120
    const size_t xh_bytes = (size_t)TOTAL_NODES * sizeof(H8);         // 6.4 MB
    float* Wc = (float*)d_ws;

    hipLaunchKernelGGL(wc_precompute, dim3(5), dim3(256), 0, stream, W1, W, Wc);

    if (ws_size >= wc_bytes + xh_bytes) {
        H8* xh = (H8*)((char*)d_ws + wc_bytes);   // 5120 % 16 == 0
        hipLaunchKernelGGL(xpack_f16, dim3((TOTAL_NODES + 255) / 256), dim3(256),
                           0, stream, x, xh);
        // Exact dispatch: 50000 waves, 4 waves/block -> 12500 blocks.
        hipLaunchKernelGGL(encoder_v3, dim3(GROUPS / 4), dim3(256), 0, stream,
                           idx, xh, Wc, b, out);
    } else {
        hipLaunchKernelGGL(encoder_f32, dim3(2048), dim3(256), 0, stream,
                           x, idx, Wc, b, out, S_ * N_ / 2);
    }
}